// Round 1
// baseline (128.566 us; speedup 1.0000x reference)
//
#include <hip/hip_runtime.h>

// ForwardKinematics fp32: rotations (B,24,4) wxyz + positions (B,24,3)
// -> global joint positions (B,24,3). Fixed SMPL tree.
//
// Round 7: coalesced INPUT staging (mirror of round-6 store fix).
//  - Phase 0: dense dwordx4 loads (1KB/wave/instr) -> LDS, odd pitches
//    (rot 97, pos 73 dwords/sample) -> conflict-free per-sample reads.
//  - 4 threads/sample (4 waves, wave-uniform subtree split, 34 mats total).
//  - Outputs overwrite the pos LDS region (pos pre-gathered to regs,
//    one barrier protects cross-wave spine reads).
//  - Phase 2: dense dwordx4 stores (full-line coverage, no RFO).
//  - LDS 43.5KB -> 3 blocks/CU = 12 waves/CU.

typedef float f32x4 __attribute__((ext_vector_type(4)));

struct M { float r0,r1,r2,r3,r4,r5,r6,r7,r8,tx,ty,tz; };

__device__ __forceinline__ M loc(float a, float b, float c, float d,
                                 float px, float py, float pz) {
    float inv = rsqrtf(a*a + b*b + c*c + d*d);
    float qw = a*inv, qx = b*inv, qy = c*inv, qz = d*inv;
    float x2 = qx+qx, y2 = qy+qy, z2 = qz+qz;
    float xx = qx*x2, yy = qy*y2, zz = qz*z2;
    float xy = qx*y2, yz = qy*z2, xz = qx*z2;
    float wx = qw*x2, wy = qw*y2, wz = qw*z2;
    M m;
    m.r0 = 1.f-(yy+zz); m.r1 = xy-wz;       m.r2 = xz+wy;
    m.r3 = xy+wz;       m.r4 = 1.f-(xx+zz); m.r5 = yz-wx;
    m.r6 = xz-wy;       m.r7 = yz+wx;       m.r8 = 1.f-(xx+yy);
    m.tx = px; m.ty = py; m.tz = pz;
    return m;
}

__device__ __forceinline__ M mul(const M& a, const M& b) {
    M c;
    c.r0 = a.r0*b.r0 + a.r1*b.r3 + a.r2*b.r6;
    c.r1 = a.r0*b.r1 + a.r1*b.r4 + a.r2*b.r7;
    c.r2 = a.r0*b.r2 + a.r1*b.r5 + a.r2*b.r8;
    c.r3 = a.r3*b.r0 + a.r4*b.r3 + a.r5*b.r6;
    c.r4 = a.r3*b.r1 + a.r4*b.r4 + a.r5*b.r7;
    c.r5 = a.r3*b.r2 + a.r4*b.r5 + a.r5*b.r8;
    c.r6 = a.r6*b.r0 + a.r7*b.r3 + a.r8*b.r6;
    c.r7 = a.r6*b.r1 + a.r7*b.r4 + a.r8*b.r7;
    c.r8 = a.r6*b.r2 + a.r7*b.r5 + a.r8*b.r8;
    c.tx = a.r0*b.tx + a.r1*b.ty + a.r2*b.tz + a.tx;
    c.ty = a.r3*b.tx + a.r4*b.ty + a.r5*b.tz + a.ty;
    c.tz = a.r6*b.tx + a.r7*b.ty + a.r8*b.tz + a.tz;
    return c;
}

#define SPB    64
#define RPITCH 97   // 96 quat dwords + 1 pad (odd -> conflict-free)
#define PPITCH 73   // 72 pos/out dwords + 1 pad

// Wave-uniform 4-way tree split. MT = matrices computed (topological),
// PR = parent index into MT (-1 = root), writes are the suffix from WS.
// Output sets: g0 {0,1,2,4,7,10} g1 {5,8,11,3,6,9} g2 {12,15,13,16,18,20,22}
// g3 {14,17,19,21,23} -> each of 24 joints written exactly once.
constexpr int MT0[6]  = {0,1,2,4,7,10};
constexpr int PR0[6]  = {-1,0,0,1,3,4};
constexpr int MT1[8]  = {0,2,5,8,11,3,6,9};
constexpr int PR1[8]  = {-1,0,1,2,3,0,5,6};
constexpr int MT2[11] = {0,3,6,9,12,15,13,16,18,20,22};
constexpr int PR2[11] = {-1,0,1,2,3,4,3,6,7,8,9};
constexpr int MT3[9]  = {0,3,6,9,14,17,19,21,23};
constexpr int PR3[9]  = {-1,0,1,2,3,4,5,6,7};

template<int NM>
__device__ __forceinline__ void read_pos(const int (&MT)[NM],
                                         const float* __restrict__ P,
                                         float* __restrict__ pb) {
#pragma unroll
    for (int k = 0; k < NM; ++k) {
        pb[3*k+0] = P[3*MT[k]+0];
        pb[3*k+1] = P[3*MT[k]+1];
        pb[3*k+2] = P[3*MT[k]+2];
    }
}

template<int NM>
__device__ __forceinline__ void run_chain(const int (&MT)[NM], const int (&PR)[NM],
                                          int WS,
                                          const float* __restrict__ R,
                                          const float* __restrict__ pb,
                                          float* __restrict__ O) {
    M G[NM];
    G[0] = loc(R[0], R[1], R[2], R[3], pb[0], pb[1], pb[2]);
    if (WS == 0) { O[0]=G[0].tx; O[1]=G[0].ty; O[2]=G[0].tz; }
#pragma unroll
    for (int k = 1; k < NM; ++k) {
        const int j = MT[k];
        M L = loc(R[4*j], R[4*j+1], R[4*j+2], R[4*j+3],
                  pb[3*k], pb[3*k+1], pb[3*k+2]);
        G[k] = mul(G[PR[k]], L);
        if (k >= WS) { O[3*j]=G[k].tx; O[3*j+1]=G[k].ty; O[3*j+2]=G[k].tz; }
    }
}

__global__ __launch_bounds__(256, 3) void fk_kernel(
    const float* __restrict__ rot,   // B*96 floats (quat wxyz per joint)
    const float* __restrict__ pos,   // B*72 floats
    float*       __restrict__ out,   // B*72 floats
    int B)
{
    __shared__ float ldsR[SPB * RPITCH];   // 24832 B
    __shared__ float ldsP[SPB * PPITCH];   // 18688 B (pos, then reused as out)

    const int t = threadIdx.x;
    const size_t baseR = (size_t)blockIdx.x * (SPB*96);
    const size_t baseP = (size_t)blockIdx.x * (SPB*72);
    const size_t limR  = (size_t)B * 96;
    const size_t limP  = (size_t)B * 72;

    // ---- phase 0: dense coalesced stage-in (11 independent x4 loads) ----
    f32x4 vr[6], vp[5];
#pragma unroll
    for (int i = 0; i < 6; ++i) {
        const size_t gi = baseR + (size_t)(i*1024 + 4*t);
        f32x4 v = {0.f,0.f,0.f,0.f};
        if (gi < limR) v = *(const f32x4*)(rot + gi);
        vr[i] = v;
    }
#pragma unroll
    for (int i = 0; i < 5; ++i) {
        const size_t gi = baseP + (size_t)(i*1024 + 4*t);
        f32x4 v = {0.f,0.f,0.f,0.f};
        if ((i < 4 || t < 128) && gi < limP) v = *(const f32x4*)(pos + gi);
        vp[i] = v;
    }
    // scatter to pitched LDS (x4 chunks never straddle a sample: 96%4==72%4==0)
#pragma unroll
    for (int i = 0; i < 6; ++i) {
        const int f = i*1024 + 4*t;
        const int s = f / 96, r = f - 96*s;
        float* d = ldsR + s*RPITCH + r;
        d[0]=vr[i].x; d[1]=vr[i].y; d[2]=vr[i].z; d[3]=vr[i].w;
    }
#pragma unroll
    for (int i = 0; i < 5; ++i) {
        if (i < 4 || t < 128) {
            const int f = i*1024 + 4*t;
            const int s = f / 72, r = f - 72*s;
            float* d = ldsP + s*PPITCH + r;
            d[0]=vp[i].x; d[1]=vp[i].y; d[2]=vp[i].z; d[3]=vp[i].w;
        }
    }
    __syncthreads();

    // ---- phase 1: compute. wave w = subtree group, lane l = sample ----
    const int w = t >> 6, l = t & 63;
    const int b = blockIdx.x * SPB + l;
    const bool act = (b < B);
    const float* R = ldsR + l * RPITCH;
    const float* P = ldsP + l * PPITCH;
    float*       O = ldsP + l * PPITCH;   // outputs overwrite pos region

    float pb[33];   // gather pos first: protects cross-wave spine reads
    if (act) {
        switch (w) {
            case 0:  read_pos(MT0, P, pb); break;
            case 1:  read_pos(MT1, P, pb); break;
            case 2:  read_pos(MT2, P, pb); break;
            default: read_pos(MT3, P, pb); break;
        }
    }
    __syncthreads();   // all pos reads done before any output write

    if (act) {
        switch (w) {
            case 0:  run_chain(MT0, PR0, 0, R, pb, O); break;
            case 1:  run_chain(MT1, PR1, 2, R, pb, O); break;
            case 2:  run_chain(MT2, PR2, 4, R, pb, O); break;
            default: run_chain(MT3, PR3, 4, R, pb, O); break;
        }
    }
    __syncthreads();

    // ---- phase 2: dense coalesced dwordx4 store ----
#pragma unroll
    for (int n = 0; n < 5; ++n) {
        if (n < 4 || t < 128) {
            const int F = n*1024 + 4*t;            // dword in block chunk
            const int s = F / 72, r = F - 72*s;
            const size_t gi = baseP + (size_t)F;
            if (gi < limP) {
                f32x4 v = { ldsP[s*PPITCH+r+0], ldsP[s*PPITCH+r+1],
                            ldsP[s*PPITCH+r+2], ldsP[s*PPITCH+r+3] };
                *(f32x4*)(out + gi) = v;
            }
        }
    }
}

extern "C" void kernel_launch(void* const* d_in, const int* in_sizes, int n_in,
                              void* d_out, int out_size, void* d_ws, size_t ws_size,
                              hipStream_t stream) {
    const int B = out_size / 72;           // (B,24,3)
    const void* rot = nullptr;
    const void* pos = nullptr;
    for (int i = 0; i < n_in; ++i) {       // resolve by size, not order
        if      (in_sizes[i] == B * 96) rot = d_in[i];
        else if (in_sizes[i] == B * 72) pos = d_in[i];
    }
    if (!rot) rot = d_in[2];
    if (!pos) pos = d_in[1];

    const int grid = (B + SPB - 1) / SPB;  // 2048 blocks @ B=131072
    fk_kernel<<<grid, 256, 0, stream>>>(
        (const float*)rot, (const float*)pos, (float*)d_out, B);
}